// Round 6
// baseline (473.007 us; speedup 1.0000x reference)
//
#include <hip/hip_runtime.h>

#define N_NODES 100000
#define N_EDGES 3200000
#define NB_F 782                       // fine buckets: 128 dst nodes each
#define TILE 8192
#define NTILES ((N_EDGES + TILE - 1) / TILE)   // 391
#define EPT (TILE / 256)               // edges per thread per tile = 32
#define SSPLIT 4                       // sub-blocks per bucket (agg kernels)

// ---------------------------------------------------------------------------
// Workspace layout (4-byte elements):
//   ints:
//     [0,    1024)        bcnt     (zeroed; per-bucket edge counts)
//     [1024, 2048)        offsets  (exclusive scan, +total at [1024+NB_F])
//     [2048, 3072)        gcur     (running cursors, init = offsets)
//     [3072, 3072+E)      recs     (packed (local_dst<<17)|src, dst-bucketed)
//   then:
//     p1h     16N ushorts = bf16(x @ Wl1^T)  -- 3.2 MB, L2-resident
//     q1b     16N floats  = x @ Wr1^T + b1
//     p2/r2/deg_inv  N floats each
//     pacc    SSPLIT*NB_F*2048 floats, c-major within block: [c*128+local]
//     u_part  SSPLIT*NB_F*128  floats
//     pcnt    SSPLIT*NB_F*128  ints
// ---------------------------------------------------------------------------

__device__ __forceinline__ float bf2f_lo(unsigned int w) {
  return __uint_as_float(w << 16);
}
__device__ __forceinline__ float bf2f_hi(unsigned int w) {
  return __uint_as_float(w & 0xFFFF0000u);
}
__device__ __forceinline__ unsigned short f2bf(float f) {
  unsigned int b = __float_as_uint(f);
  return (unsigned short)((b + 0x7FFFu + ((b >> 16) & 1u)) >> 16);
}

__global__ __launch_bounds__(256) void k_proj1(
    const float* __restrict__ x, const float* __restrict__ Wl1,
    const float* __restrict__ Wr1, const float* __restrict__ b1,
    unsigned short* __restrict__ p1h, float* __restrict__ q1b) {
  __shared__ float sWl[16 * 32];
  __shared__ float sWr[16 * 32];
  __shared__ float sb[16];
  const int t = threadIdx.x;
  for (int i = t; i < 512; i += 256) {
    sWl[i] = Wl1[i];
    sWr[i] = Wr1[i];
  }
  if (t < 16) sb[t] = b1[t];
  __syncthreads();

  const int n = blockIdx.x * 256 + t;
  if (n >= N_NODES) return;

  float xr[32];
  const float4* xp = (const float4*)(x + (size_t)n * 32);
#pragma unroll
  for (int j = 0; j < 8; ++j) {
    float4 v = xp[j];
    xr[4 * j + 0] = v.x;
    xr[4 * j + 1] = v.y;
    xr[4 * j + 2] = v.z;
    xr[4 * j + 3] = v.w;
  }

  float pv[16], qv[16];
#pragma unroll
  for (int hh = 0; hh < 16; ++hh) {
    float a = 0.f, b = 0.f;
#pragma unroll
    for (int i = 0; i < 32; ++i) {
      a = fmaf(xr[i], sWl[hh * 32 + i], a);
      b = fmaf(xr[i], sWr[hh * 32 + i], b);
    }
    pv[hh] = a;
    qv[hh] = b + sb[hh];
  }

  unsigned int w[8];
#pragma unroll
  for (int j = 0; j < 8; ++j)
    w[j] = (unsigned int)f2bf(pv[2 * j]) |
           ((unsigned int)f2bf(pv[2 * j + 1]) << 16);
  uint4* pp = (uint4*)(p1h + (size_t)n * 16);
  pp[0] = make_uint4(w[0], w[1], w[2], w[3]);
  pp[1] = make_uint4(w[4], w[5], w[6], w[7]);

  float4* qp = (float4*)(q1b + (size_t)n * 16);
#pragma unroll
  for (int j = 0; j < 4; ++j)
    qp[j] = make_float4(qv[4 * j], qv[4 * j + 1], qv[4 * j + 2], qv[4 * j + 3]);
}

__global__ __launch_bounds__(256) void k_bhist(const int* __restrict__ dst,
                                               int* __restrict__ bcnt) {
  __shared__ int cnt[NB_F];
  const int t = threadIdx.x;
  for (int i = t; i < NB_F; i += 256) cnt[i] = 0;
  __syncthreads();
  const int tb = blockIdx.x * TILE;
#pragma unroll
  for (int i = 0; i < EPT; ++i) {
    const int e = tb + t + i * 256;
    if (e < N_EDGES) atomicAdd(&cnt[dst[e] >> 7], 1);
  }
  __syncthreads();
  for (int i = t; i < NB_F; i += 256)
    if (cnt[i]) atomicAdd(&bcnt[i], cnt[i]);
}

__global__ __launch_bounds__(1024) void k_bscan(const int* __restrict__ bcnt,
                                                int* __restrict__ offsets,
                                                int* __restrict__ gcur) {
  __shared__ int sm[1024];
  const int t = threadIdx.x;
  const int v = (t < NB_F) ? bcnt[t] : 0;
  sm[t] = v;
  __syncthreads();
#pragma unroll
  for (int o = 1; o < 1024; o <<= 1) {
    const int a = (t >= o) ? sm[t - o] : 0;
    __syncthreads();
    sm[t] += a;
    __syncthreads();
  }
  if (t < NB_F) {
    const int ex = sm[t] - v;
    offsets[t] = ex;
    gcur[t] = ex;
    if (t == NB_F - 1) offsets[NB_F] = sm[t];
  }
}

__global__ __launch_bounds__(256) void k_bscatter(const int* __restrict__ ei,
                                                  int* __restrict__ gcur,
                                                  int* __restrict__ recs) {
  __shared__ int cnt[NB_F];
  __shared__ int rbase[NB_F];
  const int t = threadIdx.x;
  for (int i = t; i < NB_F; i += 256) cnt[i] = 0;
  __syncthreads();
  const int tb = blockIdx.x * TILE;
  int ds[EPT];
#pragma unroll
  for (int i = 0; i < EPT; ++i) {
    const int e = tb + t + i * 256;
    ds[i] = (e < N_EDGES) ? ei[N_EDGES + e] : -1;
    if (ds[i] >= 0) atomicAdd(&cnt[ds[i] >> 7], 1);
  }
  __syncthreads();
  for (int i = t; i < NB_F; i += 256) {
    const int c = cnt[i];
    if (c) rbase[i] = atomicAdd(&gcur[i], c);
  }
  __syncthreads();
#pragma unroll
  for (int i = 0; i < EPT; ++i) {
    const int e = tb + t + i * 256;
    if (e < N_EDGES) {
      const int d = ds[i];
      const int s = ei[e];
      const int k = d >> 7;
      const int slot = atomicAdd(&cnt[k], -1) - 1;
      recs[rbase[k] + slot] = ((d & 127) << 17) | s;
    }
  }
}

// layer-1 aggregation, one LANE per record: lane loads rec + full 32B bf16
// row (2x dwordx4), then 16 fire-and-forget LDS atomics into c-major acc.
// One 64-divergent vmem instr serves 64 records (was 4) -> ~6x less TA work.
__global__ __launch_bounds__(256) void k_agg1(
    const int* __restrict__ offsets, const int* __restrict__ recs,
    const unsigned short* __restrict__ p1h, float* __restrict__ pacc,
    int* __restrict__ pcnt) {
  __shared__ float acc[2048];   // [c*128 + local]
  __shared__ int cntL[128];
  const int t = threadIdx.x;
  for (int i = t; i < 2048; i += 256) acc[i] = 0.f;
  if (t < 128) cntL[t] = 0;
  __syncthreads();

  const int kb = blockIdx.x >> 2;
  const int s = blockIdx.x & 3;
  const int o0 = offsets[kb];
  const int len = offsets[kb + 1] - o0;
  const int cb = o0 + (len * s) / SSPLIT;
  const int ce = o0 + (len * (s + 1)) / SSPLIT;

  int r = cb + t;
  for (; r + 256 < ce; r += 512) {
    const int rec0 = recs[r];
    const int rec1 = recs[r + 256];
    const uint4* row0 = (const uint4*)(p1h + (size_t)(rec0 & 0x1FFFF) * 16);
    const uint4* row1 = (const uint4*)(p1h + (size_t)(rec1 & 0x1FFFF) * 16);
    const uint4 a0 = row0[0], b0 = row0[1];
    const uint4 a1 = row1[0], b1 = row1[1];
    const int l0 = rec0 >> 17;
    const int l1 = rec1 >> 17;
    const unsigned int w0[8] = {a0.x, a0.y, a0.z, a0.w, b0.x, b0.y, b0.z, b0.w};
    const unsigned int w1[8] = {a1.x, a1.y, a1.z, a1.w, b1.x, b1.y, b1.z, b1.w};
#pragma unroll
    for (int j = 0; j < 8; ++j) {
      atomicAdd(&acc[(2 * j) * 128 + l0], bf2f_lo(w0[j]));
      atomicAdd(&acc[(2 * j + 1) * 128 + l0], bf2f_hi(w0[j]));
      atomicAdd(&acc[(2 * j) * 128 + l1], bf2f_lo(w1[j]));
      atomicAdd(&acc[(2 * j + 1) * 128 + l1], bf2f_hi(w1[j]));
    }
    atomicAdd(&cntL[l0], 1);
    atomicAdd(&cntL[l1], 1);
  }
  for (; r < ce; r += 256) {
    const int rec = recs[r];
    const uint4* row = (const uint4*)(p1h + (size_t)(rec & 0x1FFFF) * 16);
    const uint4 a = row[0], b = row[1];
    const int l = rec >> 17;
    const unsigned int w[8] = {a.x, a.y, a.z, a.w, b.x, b.y, b.z, b.w};
#pragma unroll
    for (int j = 0; j < 8; ++j) {
      atomicAdd(&acc[(2 * j) * 128 + l], bf2f_lo(w[j]));
      atomicAdd(&acc[(2 * j + 1) * 128 + l], bf2f_hi(w[j]));
    }
    atomicAdd(&cntL[l], 1);
  }
  __syncthreads();

  float* dst = pacc + ((size_t)(s * NB_F + kb) << 11);
  for (int i = t; i < 2048; i += 256) dst[i] = acc[i];
  if (t < 128) pcnt[((size_t)(s * NB_F + kb) << 7) + t] = cntL[t];
}

// finalize layer 1: thread-per-node, coalesced c-major partial reads,
// fused relu + p2/r2/deg_inv (h never stored)
__global__ __launch_bounds__(256) void k_fin1(
    const float* __restrict__ pacc, const int* __restrict__ pcnt,
    const float* __restrict__ q1b, const float* __restrict__ Wl2,
    const float* __restrict__ Wr2, float* __restrict__ p2,
    float* __restrict__ r2, float* __restrict__ deg_inv) {
  __shared__ float sWl[16], sWr[16];
  const int t = threadIdx.x;
  if (t < 16) {
    sWl[t] = Wl2[t];
    sWr[t] = Wr2[t];
  }
  __syncthreads();
  const int n = blockIdx.x * 256 + t;
  if (n >= N_NODES) return;
  const int kb = n >> 7;
  const int local = n & 127;

  float acc[16];
#pragma unroll
  for (int c = 0; c < 16; ++c) acc[c] = 0.f;
  int cnt = 0;
#pragma unroll
  for (int s = 0; s < SSPLIT; ++s) {
    const float* base = pacc + (((size_t)(s * NB_F + kb)) << 11);
#pragma unroll
    for (int c = 0; c < 16; ++c) acc[c] += base[c * 128 + local];
    cnt += pcnt[(((size_t)(s * NB_F + kb)) << 7) + local];
  }
  const float di = 1.f / fmaxf((float)cnt, 1.f);

  const float4* qp = (const float4*)(q1b + (size_t)n * 16);
  float a = 0.f, b = 0.f;
#pragma unroll
  for (int j = 0; j < 4; ++j) {
    const float4 q = qp[j];
    const float h0 = fmaxf(fmaf(acc[4 * j + 0], di, q.x), 0.f);
    const float h1 = fmaxf(fmaf(acc[4 * j + 1], di, q.y), 0.f);
    const float h2 = fmaxf(fmaf(acc[4 * j + 2], di, q.z), 0.f);
    const float h3 = fmaxf(fmaf(acc[4 * j + 3], di, q.w), 0.f);
    a = fmaf(h0, sWl[4 * j + 0], a);
    a = fmaf(h1, sWl[4 * j + 1], a);
    a = fmaf(h2, sWl[4 * j + 2], a);
    a = fmaf(h3, sWl[4 * j + 3], a);
    b = fmaf(h0, sWr[4 * j + 0], b);
    b = fmaf(h1, sWr[4 * j + 1], b);
    b = fmaf(h2, sWr[4 * j + 2], b);
    b = fmaf(h3, sWr[4 * j + 3], b);
  }
  p2[n] = a;
  r2[n] = b;
  deg_inv[n] = di;
}

// layer-2 aggregation: already one-lane-per-record; p2 (400 KB) L2-resident
__global__ __launch_bounds__(256) void k_agg2(
    const int* __restrict__ offsets, const int* __restrict__ recs,
    const float* __restrict__ p2, float* __restrict__ u_part) {
  __shared__ float u[128];
  const int t = threadIdx.x;
  if (t < 128) u[t] = 0.f;
  __syncthreads();
  const int kb = blockIdx.x >> 2;
  const int s = blockIdx.x & 3;
  const int o0 = offsets[kb];
  const int len = offsets[kb + 1] - o0;
  const int cb = o0 + (len * s) / SSPLIT;
  const int ce = o0 + (len * (s + 1)) / SSPLIT;

  int r = cb + t;
  for (; r + 768 < ce; r += 1024) {
    const int rec0 = recs[r];
    const int rec1 = recs[r + 256];
    const int rec2 = recs[r + 512];
    const int rec3 = recs[r + 768];
    const float v0 = p2[rec0 & 0x1FFFF];
    const float v1 = p2[rec1 & 0x1FFFF];
    const float v2 = p2[rec2 & 0x1FFFF];
    const float v3 = p2[rec3 & 0x1FFFF];
    atomicAdd(&u[rec0 >> 17], v0);
    atomicAdd(&u[rec1 >> 17], v1);
    atomicAdd(&u[rec2 >> 17], v2);
    atomicAdd(&u[rec3 >> 17], v3);
  }
  for (; r < ce; r += 256) {
    const int rec = recs[r];
    atomicAdd(&u[rec >> 17], p2[rec & 0x1FFFF]);
  }
  __syncthreads();
  if (t < 128) u_part[(size_t)(s * NB_F + kb) * 128 + t] = u[t];
}

__global__ __launch_bounds__(256) void k_out(
    const float* __restrict__ u_part, const float* __restrict__ r2,
    const float* __restrict__ deg_inv, const float* __restrict__ b2,
    float* __restrict__ out) {
  const int n = blockIdx.x * 256 + threadIdx.x;
  if (n >= N_NODES) return;
  float u = 0.f;
#pragma unroll
  for (int s = 0; s < SSPLIT; ++s) u += u_part[(size_t)s * NB_F * 128 + n];
  out[n] = fmaf(u, deg_inv[n], r2[n] + b2[0]);
}

extern "C" void kernel_launch(void* const* d_in, const int* in_sizes, int n_in,
                              void* d_out, int out_size, void* d_ws,
                              size_t ws_size, hipStream_t stream) {
  const float* x   = (const float*)d_in[0];
  const int*   ei  = (const int*)d_in[1];
  const float* Wl1 = (const float*)d_in[2];
  const float* Wr1 = (const float*)d_in[3];
  const float* b1  = (const float*)d_in[4];
  const float* Wl2 = (const float*)d_in[5];
  const float* Wr2 = (const float*)d_in[6];
  const float* b2  = (const float*)d_in[7];
  float* out = (float*)d_out;

  const size_t N = N_NODES;
  int* wi = (int*)d_ws;
  int* bcnt    = wi;
  int* offsets = wi + 1024;
  int* gcur    = wi + 2048;
  int* recs    = wi + 3072;
  unsigned short* p1h = (unsigned short*)(recs + N_EDGES);
  float* q1b     = (float*)(p1h + 16 * N);   // 16N ushorts = 8N words
  float* p2      = q1b + 16 * N;
  float* r2      = p2 + N;
  float* deg_inv = r2 + N;
  float* pacc    = deg_inv + N;
  float* u_part  = pacc + (size_t)SSPLIT * NB_F * 2048;
  int* pcnt      = (int*)(u_part + (size_t)SSPLIT * NB_F * 128);

  hipMemsetAsync(bcnt, 0, 1024 * sizeof(int), stream);

  const int nodeBlocks = (N_NODES + 255) / 256;
  k_proj1<<<nodeBlocks, 256, 0, stream>>>(x, Wl1, Wr1, b1, p1h, q1b);
  k_bhist<<<NTILES, 256, 0, stream>>>(ei + N_EDGES, bcnt);
  k_bscan<<<1, 1024, 0, stream>>>(bcnt, offsets, gcur);
  k_bscatter<<<NTILES, 256, 0, stream>>>(ei, gcur, recs);
  k_agg1<<<NB_F * SSPLIT, 256, 0, stream>>>(offsets, recs, p1h, pacc, pcnt);
  k_fin1<<<nodeBlocks, 256, 0, stream>>>(pacc, pcnt, q1b, Wl2, Wr2,
                                         p2, r2, deg_inv);
  k_agg2<<<NB_F * SSPLIT, 256, 0, stream>>>(offsets, recs, p2, u_part);
  k_out<<<nodeBlocks, 256, 0, stream>>>(u_part, r2, deg_inv, b2, out);
}

// Round 7
// 227.367 us; speedup vs baseline: 2.0804x; 2.0804x over previous
//
#include <hip/hip_runtime.h>

#define N_NODES 100000
#define N_EDGES 3200000
#define NB_F 782                       // fine buckets: 128 dst nodes each
#define TILE 8192
#define NTILES ((N_EDGES + TILE - 1) / TILE)   // 391
#define EPT (TILE / 256)               // edges per thread per tile = 32

// ---------------------------------------------------------------------------
// Workspace layout (4-byte elements):
//   [0,    1024)        bcnt      (zeroed; per-bucket edge counts)
//   [1024, 2048)        offsets   (exclusive scan, +total at [1024+NB_F])
//   [2048, 3072)        gcur      (running cursors, init = offsets)
//   [3072, 3072+100104) node_off  (global CSR offsets, NB_F*128+1 used)
//   then recs[E]        (packed (local_dst<<17)|src, bucket-sorted)
//   then srclist[E]     (src per edge, NODE-sorted)
//   then p1h  16N ushorts = bf16(x @ Wl1^T)   (3.2 MB, L2-resident)
//        q1b  16N floats  = x @ Wr1^T + b1
//        p2    N floats    r2  N floats
// ---------------------------------------------------------------------------

#define NODEOFF_OFF 3072
#define RECS_OFF (NODEOFF_OFF + 100104)

__device__ __forceinline__ float bf2f_lo(unsigned int w) {
  return __uint_as_float(w << 16);
}
__device__ __forceinline__ float bf2f_hi(unsigned int w) {
  return __uint_as_float(w & 0xFFFF0000u);
}
__device__ __forceinline__ unsigned short f2bf(float f) {
  unsigned int b = __float_as_uint(f);
  return (unsigned short)((b + 0x7FFFu + ((b >> 16) & 1u)) >> 16);
}

__global__ __launch_bounds__(256) void k_proj1(
    const float* __restrict__ x, const float* __restrict__ Wl1,
    const float* __restrict__ Wr1, const float* __restrict__ b1,
    unsigned short* __restrict__ p1h, float* __restrict__ q1b) {
  __shared__ float sWl[16 * 32];
  __shared__ float sWr[16 * 32];
  __shared__ float sb[16];
  const int t = threadIdx.x;
  for (int i = t; i < 512; i += 256) {
    sWl[i] = Wl1[i];
    sWr[i] = Wr1[i];
  }
  if (t < 16) sb[t] = b1[t];
  __syncthreads();

  const int n = blockIdx.x * 256 + t;
  if (n >= N_NODES) return;

  float xr[32];
  const float4* xp = (const float4*)(x + (size_t)n * 32);
#pragma unroll
  for (int j = 0; j < 8; ++j) {
    float4 v = xp[j];
    xr[4 * j + 0] = v.x;
    xr[4 * j + 1] = v.y;
    xr[4 * j + 2] = v.z;
    xr[4 * j + 3] = v.w;
  }

  float pv[16], qv[16];
#pragma unroll
  for (int hh = 0; hh < 16; ++hh) {
    float a = 0.f, b = 0.f;
#pragma unroll
    for (int i = 0; i < 32; ++i) {
      a = fmaf(xr[i], sWl[hh * 32 + i], a);
      b = fmaf(xr[i], sWr[hh * 32 + i], b);
    }
    pv[hh] = a;
    qv[hh] = b + sb[hh];
  }

  unsigned int w[8];
#pragma unroll
  for (int j = 0; j < 8; ++j)
    w[j] = (unsigned int)f2bf(pv[2 * j]) |
           ((unsigned int)f2bf(pv[2 * j + 1]) << 16);
  uint4* pp = (uint4*)(p1h + (size_t)n * 16);
  pp[0] = make_uint4(w[0], w[1], w[2], w[3]);
  pp[1] = make_uint4(w[4], w[5], w[6], w[7]);

  float4* qp = (float4*)(q1b + (size_t)n * 16);
#pragma unroll
  for (int j = 0; j < 4; ++j)
    qp[j] = make_float4(qv[4 * j], qv[4 * j + 1], qv[4 * j + 2], qv[4 * j + 3]);
}

__global__ __launch_bounds__(256) void k_bhist(const int* __restrict__ dst,
                                               int* __restrict__ bcnt) {
  __shared__ int cnt[NB_F];
  const int t = threadIdx.x;
  for (int i = t; i < NB_F; i += 256) cnt[i] = 0;
  __syncthreads();
  const int tb = blockIdx.x * TILE;
#pragma unroll
  for (int i = 0; i < EPT; ++i) {
    const int e = tb + t + i * 256;
    if (e < N_EDGES) atomicAdd(&cnt[dst[e] >> 7], 1);
  }
  __syncthreads();
  for (int i = t; i < NB_F; i += 256)
    if (cnt[i]) atomicAdd(&bcnt[i], cnt[i]);
}

__global__ __launch_bounds__(1024) void k_bscan(const int* __restrict__ bcnt,
                                                int* __restrict__ offsets,
                                                int* __restrict__ gcur) {
  __shared__ int sm[1024];
  const int t = threadIdx.x;
  const int v = (t < NB_F) ? bcnt[t] : 0;
  sm[t] = v;
  __syncthreads();
#pragma unroll
  for (int o = 1; o < 1024; o <<= 1) {
    const int a = (t >= o) ? sm[t - o] : 0;
    __syncthreads();
    sm[t] += a;
    __syncthreads();
  }
  if (t < NB_F) {
    const int ex = sm[t] - v;
    offsets[t] = ex;
    gcur[t] = ex;
    if (t == NB_F - 1) offsets[NB_F] = sm[t];
  }
}

__global__ __launch_bounds__(256) void k_bscatter(const int* __restrict__ ei,
                                                  int* __restrict__ gcur,
                                                  int* __restrict__ recs) {
  __shared__ int cnt[NB_F];
  __shared__ int rbase[NB_F];
  const int t = threadIdx.x;
  for (int i = t; i < NB_F; i += 256) cnt[i] = 0;
  __syncthreads();
  const int tb = blockIdx.x * TILE;
  int ds[EPT];
#pragma unroll
  for (int i = 0; i < EPT; ++i) {
    const int e = tb + t + i * 256;
    ds[i] = (e < N_EDGES) ? ei[N_EDGES + e] : -1;
    if (ds[i] >= 0) atomicAdd(&cnt[ds[i] >> 7], 1);
  }
  __syncthreads();
  for (int i = t; i < NB_F; i += 256) {
    const int c = cnt[i];
    if (c) rbase[i] = atomicAdd(&gcur[i], c);
  }
  __syncthreads();
#pragma unroll
  for (int i = 0; i < EPT; ++i) {
    const int e = tb + t + i * 256;
    if (e < N_EDGES) {
      const int d = ds[i];
      const int s = ei[e];
      const int k = d >> 7;
      const int slot = atomicAdd(&cnt[k], -1) - 1;
      recs[rbase[k] + slot] = ((d & 127) << 17) | s;
    }
  }
}

// per-bucket counting sort by local dst -> node-contiguous srclist + CSR
// node_off. 2 LDS atomics/record, all traffic bucket-local.
__global__ __launch_bounds__(256) void k_bsort(const int* __restrict__ offsets,
                                               const int* __restrict__ recs,
                                               int* __restrict__ srclist,
                                               int* __restrict__ node_off) {
  __shared__ int hist[128];
  __shared__ int scn[128];
  __shared__ int cur[128];
  const int t = threadIdx.x;
  const int kb = blockIdx.x;
  if (t < 128) hist[t] = 0;
  __syncthreads();
  const int o0 = offsets[kb];
  const int o1 = offsets[kb + 1];
  for (int r = o0 + t; r < o1; r += 256) atomicAdd(&hist[recs[r] >> 17], 1);
  __syncthreads();
  if (t < 128) scn[t] = hist[t];
  __syncthreads();
#pragma unroll
  for (int o = 1; o < 128; o <<= 1) {
    const int v = (t < 128 && t >= o) ? scn[t - o] : 0;
    __syncthreads();
    if (t < 128) scn[t] += v;
    __syncthreads();
  }
  if (t < 128) {
    const int ex = scn[t] - hist[t];  // exclusive scan
    cur[t] = ex;
    node_off[kb * 128 + t] = o0 + ex;
  }
  if (t == 0 && kb == NB_F - 1) node_off[NB_F * 128] = o1;
  __syncthreads();
  for (int r = o0 + t; r < o1; r += 256) {
    const int rec = recs[r];
    const int slot = atomicAdd(&cur[rec >> 17], 1);
    srclist[o0 + slot] = rec & 0x1FFFF;
  }
}

// layer-1 aggregation: 4 lanes/node, REGISTER accumulation (no LDS atomics),
// fused relu + p2 = h@Wl2^T + r2 = h@Wr2^T. h never materialized.
__global__ __launch_bounds__(256) void k_agg1(
    const int* __restrict__ node_off, const int* __restrict__ srclist,
    const unsigned short* __restrict__ p1h, const float* __restrict__ q1b,
    const float* __restrict__ Wl2, const float* __restrict__ Wr2,
    float* __restrict__ p2, float* __restrict__ r2) {
  __shared__ float sWl[16], sWr[16];
  const int t = threadIdx.x;
  if (t < 16) {
    sWl[t] = Wl2[t];
    sWr[t] = Wr2[t];
  }
  __syncthreads();
  const int n = blockIdx.x * 64 + (t >> 2);
  const int c = t & 3;  // lane owns channels 4c..4c+3
  if (n >= N_NODES) return;
  const int k0 = node_off[n];
  const int k = node_off[n + 1] - k0;
  const int* sl = srclist + k0;
  const unsigned short* pb = p1h + c * 4;

  float a0 = 0.f, a1 = 0.f, a2 = 0.f, a3 = 0.f;
  int j = 0;
  for (; j + 4 <= k; j += 4) {
    const int s0 = sl[j], s1 = sl[j + 1], s2 = sl[j + 2], s3 = sl[j + 3];
    const uint2 w0 = *(const uint2*)(pb + (size_t)s0 * 16);
    const uint2 w1 = *(const uint2*)(pb + (size_t)s1 * 16);
    const uint2 w2 = *(const uint2*)(pb + (size_t)s2 * 16);
    const uint2 w3 = *(const uint2*)(pb + (size_t)s3 * 16);
    a0 += (bf2f_lo(w0.x) + bf2f_lo(w1.x)) + (bf2f_lo(w2.x) + bf2f_lo(w3.x));
    a1 += (bf2f_hi(w0.x) + bf2f_hi(w1.x)) + (bf2f_hi(w2.x) + bf2f_hi(w3.x));
    a2 += (bf2f_lo(w0.y) + bf2f_lo(w1.y)) + (bf2f_lo(w2.y) + bf2f_lo(w3.y));
    a3 += (bf2f_hi(w0.y) + bf2f_hi(w1.y)) + (bf2f_hi(w2.y) + bf2f_hi(w3.y));
  }
  for (; j < k; ++j) {
    const uint2 w = *(const uint2*)(pb + (size_t)sl[j] * 16);
    a0 += bf2f_lo(w.x);
    a1 += bf2f_hi(w.x);
    a2 += bf2f_lo(w.y);
    a3 += bf2f_hi(w.y);
  }

  const float di = 1.f / fmaxf((float)k, 1.f);
  const float4 q = ((const float4*)(q1b + (size_t)n * 16))[c];
  const float h0 = fmaxf(fmaf(a0, di, q.x), 0.f);
  const float h1 = fmaxf(fmaf(a1, di, q.y), 0.f);
  const float h2 = fmaxf(fmaf(a2, di, q.z), 0.f);
  const float h3 = fmaxf(fmaf(a3, di, q.w), 0.f);
  float pa = h0 * sWl[4 * c] + h1 * sWl[4 * c + 1] + h2 * sWl[4 * c + 2] +
             h3 * sWl[4 * c + 3];
  float pbv = h0 * sWr[4 * c] + h1 * sWr[4 * c + 1] + h2 * sWr[4 * c + 2] +
              h3 * sWr[4 * c + 3];
  pa += __shfl_xor(pa, 1);
  pa += __shfl_xor(pa, 2);
  pbv += __shfl_xor(pbv, 1);
  pbv += __shfl_xor(pbv, 2);
  if (c == 0) {
    p2[n] = pa;
    r2[n] = pbv;
  }
}

// layer-2 aggregation + output epilogue: 4 lanes/node, register accumulation
__global__ __launch_bounds__(256) void k_agg2out(
    const int* __restrict__ node_off, const int* __restrict__ srclist,
    const float* __restrict__ p2, const float* __restrict__ r2,
    const float* __restrict__ b2, float* __restrict__ out) {
  const int t = threadIdx.x;
  const int n = blockIdx.x * 64 + (t >> 2);
  const int c = t & 3;
  if (n >= N_NODES) return;
  const int k0 = node_off[n];
  const int k = node_off[n + 1] - k0;
  const int* sl = srclist + k0;

  float u = 0.f;
  int j = c;
  for (; j + 4 < k; j += 8) {
    const int sA = sl[j];
    const int sB = sl[j + 4];
    u += p2[sA] + p2[sB];
  }
  for (; j < k; j += 4) u += p2[sl[j]];
  u += __shfl_xor(u, 1);
  u += __shfl_xor(u, 2);
  if (c == 0) {
    const float di = 1.f / fmaxf((float)k, 1.f);
    out[n] = fmaf(u, di, r2[n] + b2[0]);
  }
}

extern "C" void kernel_launch(void* const* d_in, const int* in_sizes, int n_in,
                              void* d_out, int out_size, void* d_ws,
                              size_t ws_size, hipStream_t stream) {
  const float* x   = (const float*)d_in[0];
  const int*   ei  = (const int*)d_in[1];
  const float* Wl1 = (const float*)d_in[2];
  const float* Wr1 = (const float*)d_in[3];
  const float* b1  = (const float*)d_in[4];
  const float* Wl2 = (const float*)d_in[5];
  const float* Wr2 = (const float*)d_in[6];
  const float* b2  = (const float*)d_in[7];
  float* out = (float*)d_out;

  const size_t N = N_NODES;
  int* wi = (int*)d_ws;
  int* bcnt     = wi;
  int* offsets  = wi + 1024;
  int* gcur     = wi + 2048;
  int* node_off = wi + NODEOFF_OFF;
  int* recs     = wi + RECS_OFF;
  int* srclist  = recs + N_EDGES;
  unsigned short* p1h = (unsigned short*)(srclist + N_EDGES);
  float* q1b = (float*)(p1h + 16 * N);   // 16N ushorts = 8N words
  float* p2  = q1b + 16 * N;
  float* r2  = p2 + N;

  hipMemsetAsync(bcnt, 0, 1024 * sizeof(int), stream);

  const int nodeBlocks = (N_NODES + 255) / 256;   // 391
  const int aggBlocks  = (N_NODES + 63) / 64;     // 1563
  k_proj1<<<nodeBlocks, 256, 0, stream>>>(x, Wl1, Wr1, b1, p1h, q1b);
  k_bhist<<<NTILES, 256, 0, stream>>>(ei + N_EDGES, bcnt);
  k_bscan<<<1, 1024, 0, stream>>>(bcnt, offsets, gcur);
  k_bscatter<<<NTILES, 256, 0, stream>>>(ei, gcur, recs);
  k_bsort<<<NB_F, 256, 0, stream>>>(offsets, recs, srclist, node_off);
  k_agg1<<<aggBlocks, 256, 0, stream>>>(node_off, srclist, p1h, q1b, Wl2, Wr2,
                                        p2, r2);
  k_agg2out<<<aggBlocks, 256, 0, stream>>>(node_off, srclist, p2, r2, b2, out);
}